// Round 2
// baseline (1227.483 us; speedup 1.0000x reference)
//
#include <hip/hip_runtime.h>
#include <hip/hip_bf16.h>

constexpr int NLAYER = 6;
constexpr int SEQ    = 128;
constexpr int NVOCAB = 32000;

// ---------------- workspace layout (float offsets; activations only) ----------------
constexpr size_t O_H    = 0;                          // [128][256]
constexpr size_t O_XZ   = O_H    + (size_t)SEQ*256;   // [128][1024]
constexpr size_t O_U    = O_XZ   + (size_t)SEQ*1024;  // [128][512]
constexpr size_t O_XDBL = O_U    + (size_t)SEQ*512;   // [128][48]
constexpr size_t O_DT   = O_XDBL + (size_t)SEQ*48;    // [128][512]
constexpr size_t O_YG   = O_DT   + (size_t)SEQ*512;   // [128][512]
constexpr size_t O_V    = O_YG   + (size_t)SEQ*512;   // [128][256]
constexpr size_t O_AH   = O_V    + (size_t)SEQ*256;   // [128][256]

enum { FB_BIAS = 1, FB_SOFTPLUS = 2, FB_RESID = 4 };

// ---------------- embedding gather (N collapses to 1: replicas stay identical) ----------------
__global__ __launch_bounds__(256) void embed_kernel(const int* __restrict__ x,
                                                    const float* __restrict__ emb,
                                                    float* __restrict__ h)
{
    int idx = blockIdx.x * 256 + threadIdx.x;     // 128*256
    int t = idx >> 8, d = idx & 255;
    h[idx] = emb[(size_t)x[t]*256 + d];
}

// ---------------- GEMM with fused LayerNorm on A (K=256 fixed) ----------------
// out[row, c] = dot(LN(h[row,:]), W[c,:]) (+bias). Block: 4 rows (1 wave each) x 64 lanes.
template <int CPT>
__global__ __launch_bounds__(256) void gemm_ln_kernel(
    const float* __restrict__ h, const float* __restrict__ lnw, const float* __restrict__ lnb,
    const float* __restrict__ W, const float* __restrict__ bias,
    float* __restrict__ out, int N)
{
    __shared__ float sA[4][256];
    int tid = threadIdx.x;
    int lane = tid & 63;
    int r = tid >> 6;
    int row = blockIdx.y * 4 + r;
    float x0 = h[row*256 + lane];
    float x1 = h[row*256 + lane + 64];
    float x2 = h[row*256 + lane + 128];
    float x3 = h[row*256 + lane + 192];
    float s = x0 + x1 + x2 + x3;
    #pragma unroll
    for (int m = 1; m < 64; m <<= 1) s += __shfl_xor(s, m);
    float mean = s * (1.0f/256.0f);
    float d0 = x0-mean, d1 = x1-mean, d2 = x2-mean, d3 = x3-mean;
    float v = d0*d0 + d1*d1 + d2*d2 + d3*d3;
    #pragma unroll
    for (int m = 1; m < 64; m <<= 1) v += __shfl_xor(v, m);
    float rstd = rsqrtf(v * (1.0f/256.0f) + 1e-5f);
    sA[r][lane]     = d0*rstd*lnw[lane]     + lnb[lane];
    sA[r][lane+64]  = d1*rstd*lnw[lane+64]  + lnb[lane+64];
    sA[r][lane+128] = d2*rstd*lnw[lane+128] + lnb[lane+128];
    sA[r][lane+192] = d3*rstd*lnw[lane+192] + lnb[lane+192];
    __syncthreads();

    int c0 = blockIdx.x * 64 * CPT + lane;
    float acc[CPT];
    #pragma unroll
    for (int j = 0; j < CPT; ++j) acc[j] = 0.0f;
    for (int k = 0; k < 256; k += 4) {
        float4 a = *(const float4*)&sA[r][k];
        #pragma unroll
        for (int j = 0; j < CPT; ++j) {
            int c = c0 + 64*j;
            float4 w = *(const float4*)&W[(size_t)c*256 + k];
            acc[j] += a.x*w.x + a.y*w.y + a.z*w.z + a.w*w.w;
        }
    }
    #pragma unroll
    for (int j = 0; j < CPT; ++j) {
        int c = c0 + 64*j;
        float val = acc[j] + (bias ? bias[c] : 0.0f);
        out[row*N + c] = val;
    }
}

// ---------------- generic small GEMM: out = A(M=128,K;lda) @ W(N,K)^T ----------------
template <int CPT>
__global__ __launch_bounds__(256) void gemm_plain_kernel(
    const float* __restrict__ A, int lda,
    const float* __restrict__ W, const float* __restrict__ bias,
    float* __restrict__ out, int N, int K, int flags)
{
    __shared__ float sA[4*512];
    int tid = threadIdx.x;
    int r0 = blockIdx.y * 4;
    for (int i = tid; i < 4*K; i += 256) {
        int rr = i / K, kk = i - rr*K;
        sA[rr*K + kk] = A[(r0+rr)*lda + kk];
    }
    __syncthreads();
    int lane = tid & 63;
    int r = tid >> 6;
    int c0 = blockIdx.x * 64 * CPT + lane;
    int   cc[CPT]; bool ok[CPT]; float acc[CPT];
    #pragma unroll
    for (int j = 0; j < CPT; ++j) { cc[j] = c0 + 64*j; ok[j] = cc[j] < N; acc[j] = 0.0f; }
    const float* sAr = sA + r*K;
    for (int k = 0; k < K; k += 4) {
        float4 a = *(const float4*)&sAr[k];
        #pragma unroll
        for (int j = 0; j < CPT; ++j) {
            if (ok[j]) {
                float4 w = *(const float4*)&W[(size_t)cc[j]*K + k];
                acc[j] += a.x*w.x + a.y*w.y + a.z*w.z + a.w*w.w;
            }
        }
    }
    int row = r0 + r;
    #pragma unroll
    for (int j = 0; j < CPT; ++j) {
        if (!ok[j]) continue;
        float val = acc[j];
        if (flags & FB_BIAS)     val += bias[cc[j]];
        if (flags & FB_SOFTPLUS) val = fmaxf(val, 0.0f) + log1pf(__expf(-fabsf(val)));
        if (flags & FB_RESID)    out[row*N + cc[j]] += val;
        else                     out[row*N + cc[j]]  = val;
    }
}

// ---------------- causal depthwise conv (DC=4) + bias + SiLU ----------------
__global__ __launch_bounds__(256) void conv_silu_kernel(
    const float* __restrict__ xz, const float* __restrict__ cw, const float* __restrict__ cb,
    float* __restrict__ u)
{
    int idx = blockIdx.x * 256 + threadIdx.x;   // 128*512
    int d = idx & 511, t = idx >> 9;
    float acc = cb[d];
    #pragma unroll
    for (int k = 0; k < 4; ++k) {
        int tt = t - 3 + k;
        if (tt >= 0) acc += xz[tt*1024 + d] * cw[d*4 + k];
    }
    float sig = 1.0f / (1.0f + __expf(-acc));
    u[idx] = acc * sig;
}

// ---------------- selective scan + skip + gate ----------------
// thread (d,s); 16 s-lanes per channel reduce via shfl_xor; yg = (y + u*D) * silu(z)
__global__ __launch_bounds__(256) void scan_kernel(
    const float* __restrict__ dt, const float* __restrict__ u, const float* __restrict__ xdbl,
    const float* __restrict__ alog, const float* __restrict__ dskip,
    const float* __restrict__ xz, float* __restrict__ yg)
{
    __shared__ float sdt[8][16], su[8][16], sz[8][16], sB[8][16], sC[8][16];
    int tid = threadIdx.x;
    int s = tid & 15, dl = tid >> 4;
    int d0 = blockIdx.x * 16;
    int d = d0 + dl;
    float a_ds = -__expf(alog[d*16 + s]);
    float dsk  = dskip[d];
    float hst = 0.0f;
    for (int t0 = 0; t0 < SEQ; t0 += 8) {
        __syncthreads();
        if (tid < 128) {
            int tt = tid >> 4, j = tid & 15;
            int t = t0 + tt;
            sdt[tt][j] = dt[t*512 + d0 + j];
            su [tt][j] = u [t*512 + d0 + j];
            sz [tt][j] = xz[t*1024 + 512 + d0 + j];
        } else {
            int q = tid - 128;
            int tt = q >> 4, j = q & 15;
            int t = t0 + tt;
            sB[tt][j] = xdbl[t*48 + 16 + j];
            sC[tt][j] = xdbl[t*48 + 32 + j];
        }
        __syncthreads();
        #pragma unroll
        for (int tt = 0; tt < 8; ++tt) {
            float dtv = sdt[tt][dl];
            float uv  = su [tt][dl];
            hst = __expf(dtv * a_ds) * hst + dtv * uv * sB[tt][s];
            float p = hst * sC[tt][s];
            p += __shfl_xor(p, 1);
            p += __shfl_xor(p, 2);
            p += __shfl_xor(p, 4);
            p += __shfl_xor(p, 8);
            if (s == 0) {
                float zv = sz[tt][dl];
                float y = p + uv * dsk;
                yg[(t0+tt)*512 + d] = y * (zv / (1.0f + __expf(-zv)));
            }
        }
    }
}

// ---------------- final LN (f32 out) ----------------
__global__ __launch_bounds__(256) void lnf_kernel(
    const float* __restrict__ h, const float* __restrict__ w, const float* __restrict__ b,
    float* __restrict__ a_head)
{
    int tid = threadIdx.x;
    int lane = tid & 63;
    int r = tid >> 6;
    int row = blockIdx.x * 4 + r;
    float x0 = h[row*256 + lane];
    float x1 = h[row*256 + lane + 64];
    float x2 = h[row*256 + lane + 128];
    float x3 = h[row*256 + lane + 192];
    float s = x0 + x1 + x2 + x3;
    #pragma unroll
    for (int m = 1; m < 64; m <<= 1) s += __shfl_xor(s, m);
    float mean = s * (1.0f/256.0f);
    float d0 = x0-mean, d1 = x1-mean, d2 = x2-mean, d3 = x3-mean;
    float v = d0*d0 + d1*d1 + d2*d2 + d3*d3;
    #pragma unroll
    for (int m = 1; m < 64; m <<= 1) v += __shfl_xor(v, m);
    float rstd = rsqrtf(v * (1.0f/256.0f) + 1e-5f);
    a_head[row*256 + lane]     = d0*rstd*w[lane]     + b[lane];
    a_head[row*256 + lane+64]  = d1*rstd*w[lane+64]  + b[lane+64];
    a_head[row*256 + lane+128] = d2*rstd*w[lane+128] + b[lane+128];
    a_head[row*256 + lane+192] = d3*rstd*w[lane+192] + b[lane+192];
}

// ---------------- head GEMM (f32): out(128,32000) = AH(128,256) @ emb(32000,256)^T + hb ----------------
// block: 16 rows x 64 cols; wave r handles 4 rows; A rows are wave-uniform L1-broadcast loads.
__global__ __launch_bounds__(256) void head_f32_kernel(
    const float* __restrict__ AH, const float* __restrict__ emb,
    const float* __restrict__ hb, float* __restrict__ out)
{
    int tid = threadIdx.x;
    int lane = tid & 63;
    int r = tid >> 6;
    int rbase = blockIdx.y * 16 + r * 4;
    int c = blockIdx.x * 64 + lane;
    const float* Wp = emb + (size_t)c * 256;
    const float* A0 = AH + (size_t)(rbase+0) * 256;
    const float* A1 = AH + (size_t)(rbase+1) * 256;
    const float* A2 = AH + (size_t)(rbase+2) * 256;
    const float* A3 = AH + (size_t)(rbase+3) * 256;
    float acc0 = 0.f, acc1 = 0.f, acc2 = 0.f, acc3 = 0.f;
    for (int k = 0; k < 256; k += 4) {
        float4 w  = *(const float4*)(Wp + k);
        float4 a0 = *(const float4*)(A0 + k);
        float4 a1 = *(const float4*)(A1 + k);
        float4 a2 = *(const float4*)(A2 + k);
        float4 a3 = *(const float4*)(A3 + k);
        acc0 += a0.x*w.x + a0.y*w.y + a0.z*w.z + a0.w*w.w;
        acc1 += a1.x*w.x + a1.y*w.y + a1.z*w.z + a1.w*w.w;
        acc2 += a2.x*w.x + a2.y*w.y + a2.z*w.z + a2.w*w.w;
        acc3 += a3.x*w.x + a3.y*w.y + a3.z*w.z + a3.w*w.w;
    }
    float bb = hb[c];
    out[(size_t)(rbase+0)*NVOCAB + c] = acc0 + bb;
    out[(size_t)(rbase+1)*NVOCAB + c] = acc1 + bb;
    out[(size_t)(rbase+2)*NVOCAB + c] = acc2 + bb;
    out[(size_t)(rbase+3)*NVOCAB + c] = acc3 + bb;
}

// ---------------- launch ----------------
extern "C" void kernel_launch(void* const* d_in, const int* in_sizes, int n_in,
                              void* d_out, int out_size, void* d_ws, size_t ws_size,
                              hipStream_t stream)
{
    const int*   xin = (const int*)d_in[0];
    const float* emb = (const float*)d_in[1];
    const float* n1w = (const float*)d_in[2];
    const float* n1b = (const float*)d_in[3];
    const float* n2w = (const float*)d_in[4];
    const float* n2b = (const float*)d_in[5];
    const float* ipw = (const float*)d_in[6];
    const float* cw  = (const float*)d_in[7];
    const float* cb  = (const float*)d_in[8];
    const float* xpw = (const float*)d_in[9];
    const float* dpw = (const float*)d_in[10];
    const float* dpb = (const float*)d_in[11];
    const float* alog= (const float*)d_in[12];
    const float* dsk = (const float*)d_in[13];
    const float* opw = (const float*)d_in[14];
    const float* aiw = (const float*)d_in[15];
    const float* aib = (const float*)d_in[16];
    const float* aow = (const float*)d_in[17];
    const float* aob = (const float*)d_in[18];
    const float* nfw = (const float*)d_in[19];
    const float* nfb = (const float*)d_in[20];
    const float* hb  = (const float*)d_in[21];
    float* ws  = (float*)d_ws;
    float* out = (float*)d_out;

    embed_kernel<<<SEQ, 256, 0, stream>>>(xin, emb, ws + O_H);

    for (int l = 0; l < NLAYER; ++l) {
        // LN1 + in_proj -> xz (128 x 1024)
        gemm_ln_kernel<4><<<dim3(4,32), 256, 0, stream>>>(
            ws+O_H, n1w + l*256, n1b + l*256, ipw + (size_t)l*1024*256, nullptr, ws+O_XZ, 1024);
        // causal conv + bias + silu -> u (128 x 512)
        conv_silu_kernel<<<256, 256, 0, stream>>>(ws+O_XZ, cw + l*512*4, cb + l*512, ws+O_U);
        // x_proj -> xdbl (128 x 48)
        gemm_plain_kernel<1><<<dim3(1,32), 256, 0, stream>>>(
            ws+O_U, 512, xpw + (size_t)l*48*512, nullptr, ws+O_XDBL, 48, 512, 0);
        // dt_proj + bias + softplus -> dt (128 x 512)
        gemm_plain_kernel<4><<<dim3(2,32), 256, 0, stream>>>(
            ws+O_XDBL, 48, dpw + (size_t)l*512*16, dpb + l*512, ws+O_DT, 512, 16, FB_BIAS|FB_SOFTPLUS);
        // selective scan + skip + gate -> yg (128 x 512)
        scan_kernel<<<32, 256, 0, stream>>>(ws+O_DT, ws+O_U, ws+O_XDBL,
                                            alog + (size_t)l*512*16, dsk + l*512, ws+O_XZ, ws+O_YG);
        // out_proj, h += ...
        gemm_plain_kernel<1><<<dim3(4,32), 256, 0, stream>>>(
            ws+O_YG, 512, opw + (size_t)l*256*512, nullptr, ws+O_H, 256, 512, FB_RESID);
        // LN2 + v-projection (+bias) -> v  (attention over N identical tokens == v)
        gemm_ln_kernel<1><<<dim3(4,32), 256, 0, stream>>>(
            ws+O_H, n2w + l*256, n2b + l*256,
            aiw + (size_t)l*768*256 + (size_t)512*256, aib + l*768 + 512, ws+O_V, 256);
        // attn_out (+bias), h += ...
        gemm_plain_kernel<1><<<dim3(4,32), 256, 0, stream>>>(
            ws+O_V, 256, aow + (size_t)l*256*256, aob + l*256, ws+O_H, 256, 256, FB_BIAS|FB_RESID);
    }

    // final LN, then head GEMM + bias -> logits (f32)
    lnf_kernel<<<32, 256, 0, stream>>>(ws+O_H, nfw, nfb, ws+O_AH);
    head_f32_kernel<<<dim3(NVOCAB/64, SEQ/16), 256, 0, stream>>>(ws+O_AH, emb, hb, out);
}

// Round 3
// 1062.613 us; speedup vs baseline: 1.1552x; 1.1552x over previous
//
#include <hip/hip_runtime.h>
#include <hip/hip_bf16.h>

constexpr int NLAYER = 6;
constexpr int SEQ    = 128;
constexpr int NVOCAB = 32000;

// ---------------- workspace layout (float offsets; activations only) ----------------
constexpr size_t O_H    = 0;                          // [128][256]
constexpr size_t O_XZ   = O_H    + (size_t)SEQ*256;   // [128][1024]
constexpr size_t O_U    = O_XZ   + (size_t)SEQ*1024;  // [128][512]
constexpr size_t O_XDBL = O_U    + (size_t)SEQ*512;   // [128][48]
constexpr size_t O_DT   = O_XDBL + (size_t)SEQ*48;    // [128][512]
constexpr size_t O_YG   = O_DT   + (size_t)SEQ*512;   // [128][512]
constexpr size_t O_V    = O_YG   + (size_t)SEQ*512;   // [128][256]
constexpr size_t O_AH   = O_V    + (size_t)SEQ*256;   // [128][256]

enum { GF_LN = 1, GF_BIAS = 2, GF_RESID = 4 };

// ---------------- embedding gather (N collapses to 1: replicas stay identical) ----------------
__global__ __launch_bounds__(256) void embed_kernel(const int* __restrict__ x,
                                                    const float* __restrict__ emb,
                                                    float* __restrict__ h)
{
    int idx = blockIdx.x * 256 + threadIdx.x;     // 128*256
    int t = idx >> 8, d = idx & 255;
    h[idx] = emb[(size_t)x[t]*256 + d];
}

// ---------------- wave-per-column GEMV: out(128,N) = [LN](A(128,K)) @ W(N,K)^T ----------------
// One wave handles CPW columns x RG rows. K spread across 64 lanes (coalesced W/A reads),
// butterfly shuffle reduce. LN / bias / residual fused.
template <int K, int RG, int CPW, int FLAGS>
__global__ __launch_bounds__(256) void gemv_kernel(
    const float* __restrict__ A,
    const float* __restrict__ lnw, const float* __restrict__ lnb,
    const float* __restrict__ W, const float* __restrict__ bias,
    float* __restrict__ out, int ldo)
{
    constexpr int K4 = K / 256;        // float4 chunks per lane (K=256 -> 1, K=512 -> 2)
    int lane = threadIdx.x & 63;
    int wv   = threadIdx.x >> 6;
    int c0 = (blockIdx.x * 4 + wv) * CPW;
    int r0 = blockIdx.y * RG;

    float4 wreg[CPW][K4];
    #pragma unroll
    for (int j = 0; j < CPW; ++j)
        #pragma unroll
        for (int i = 0; i < K4; ++i)
            wreg[j][i] = *(const float4*)&W[(size_t)(c0+j)*K + i*256 + lane*4];

    float4 lw{}, lb{};
    if constexpr (FLAGS & GF_LN) {
        static_assert(K == 256, "LN fusion assumes K==256");
        lw = *(const float4*)&lnw[lane*4];
        lb = *(const float4*)&lnb[lane*4];
    }
    float bv[CPW];
    #pragma unroll
    for (int j = 0; j < CPW; ++j) bv[j] = (FLAGS & GF_BIAS) ? bias[c0+j] : 0.0f;

    for (int rr = 0; rr < RG; ++rr) {
        int r = r0 + rr;
        float4 a[K4];
        #pragma unroll
        for (int i = 0; i < K4; ++i)
            a[i] = *(const float4*)&A[(size_t)r*K + i*256 + lane*4];

        if constexpr (FLAGS & GF_LN) {
            float s = a[0].x + a[0].y + a[0].z + a[0].w;
            float q = a[0].x*a[0].x + a[0].y*a[0].y + a[0].z*a[0].z + a[0].w*a[0].w;
            #pragma unroll
            for (int m = 1; m < 64; m <<= 1) { s += __shfl_xor(s, m); q += __shfl_xor(q, m); }
            float mean = s * (1.0f/256.0f);
            float var  = q * (1.0f/256.0f) - mean*mean;
            float rstd = rsqrtf(var + 1e-5f);
            a[0].x = (a[0].x-mean)*rstd*lw.x + lb.x;
            a[0].y = (a[0].y-mean)*rstd*lw.y + lb.y;
            a[0].z = (a[0].z-mean)*rstd*lw.z + lb.z;
            a[0].w = (a[0].w-mean)*rstd*lw.w + lb.w;
        }

        float p[CPW];
        #pragma unroll
        for (int j = 0; j < CPW; ++j) {
            p[j] = 0.0f;
            #pragma unroll
            for (int i = 0; i < K4; ++i)
                p[j] += a[i].x*wreg[j][i].x + a[i].y*wreg[j][i].y
                      + a[i].z*wreg[j][i].z + a[i].w*wreg[j][i].w;
        }
        #pragma unroll
        for (int m = 1; m < 64; m <<= 1) {
            #pragma unroll
            for (int j = 0; j < CPW; ++j) p[j] += __shfl_xor(p[j], m);
        }
        if (lane == 0) {
            #pragma unroll
            for (int j = 0; j < CPW; ++j) {
                float val = p[j] + bv[j];
                if (FLAGS & GF_RESID) out[(size_t)r*ldo + c0+j] += val;
                else                  out[(size_t)r*ldo + c0+j]  = val;
            }
        }
    }
}

// ---------------- fused conv+silu + x_proj + dt_proj+softplus (8 rows per block) ----------------
__global__ __launch_bounds__(256) void convxdt_kernel(
    const float* __restrict__ xz, const float* __restrict__ cw, const float* __restrict__ cb,
    const float* __restrict__ xpw, const float* __restrict__ dpw, const float* __restrict__ dpb,
    float* __restrict__ u_out, float* __restrict__ xdbl_out, float* __restrict__ dt_out)
{
    __shared__ float su[8][512];      // 16 KB  : u rows (post conv+silu)
    __shared__ float sx[8][48];       // 1.5 KB : xdbl rows
    __shared__ float sdpw[512][17];   // 34.8 KB: dt_proj_w, padded stride 17 (conflict-free)
    int tid = threadIdx.x;
    int t0 = blockIdx.x * 8;

    // stage dpw (coalesced read)
    for (int i = tid; i < 512*16; i += 256) sdpw[i >> 4][i & 15] = dpw[i];

    // conv + bias + silu -> su, u_out
    #pragma unroll
    for (int rep = 0; rep < 16; ++rep) {
        int idx = rep*256 + tid;
        int t = idx >> 9, d = idx & 511;
        float acc = cb[d];
        #pragma unroll
        for (int k = 0; k < 4; ++k) {
            int gt = t0 + t - 3 + k;
            if (gt >= 0) acc += xz[gt*1024 + d] * cw[d*4 + k];
        }
        float sv = acc / (1.0f + __expf(-acc));
        su[t][d] = sv;
        u_out[(t0+t)*512 + d] = sv;
    }
    __syncthreads();

    // x_proj: wave-per-column GEMV over LDS u (K=512, 48 cols)
    int lane = tid & 63, wv = tid >> 6;
    float4 lw0, lw1;
    for (int ci = 0; ci < 12; ++ci) {
        int c = wv*12 + ci;
        lw0 = *(const float4*)&xpw[(size_t)c*512 + lane*4];
        lw1 = *(const float4*)&xpw[(size_t)c*512 + 256 + lane*4];
        for (int t = 0; t < 8; ++t) {
            float4 a0 = *(const float4*)&su[t][lane*4];
            float4 a1 = *(const float4*)&su[t][256 + lane*4];
            float p = a0.x*lw0.x + a0.y*lw0.y + a0.z*lw0.z + a0.w*lw0.w
                    + a1.x*lw1.x + a1.y*lw1.y + a1.z*lw1.z + a1.w*lw1.w;
            #pragma unroll
            for (int m = 1; m < 64; m <<= 1) p += __shfl_xor(p, m);
            if (lane == 0) {
                sx[t][c] = p;
                xdbl_out[(t0+t)*48 + c] = p;
            }
        }
    }
    __syncthreads();

    // dt_proj (K=16) + bias + softplus -> dt_out
    #pragma unroll
    for (int rep = 0; rep < 16; ++rep) {
        int idx = rep*256 + tid;
        int t = idx >> 9, d = idx & 511;
        float acc = dpb[d];
        #pragma unroll
        for (int j = 0; j < 16; ++j) acc += sx[t][j] * sdpw[d][j];
        float sp = fmaxf(acc, 0.0f) + log1pf(__expf(-fabsf(acc)));
        dt_out[(t0+t)*512 + d] = sp;
    }
}

// ---------------- selective scan + skip + gate (verified round 2) ----------------
__global__ __launch_bounds__(256) void scan_kernel(
    const float* __restrict__ dt, const float* __restrict__ u, const float* __restrict__ xdbl,
    const float* __restrict__ alog, const float* __restrict__ dskip,
    const float* __restrict__ xz, float* __restrict__ yg)
{
    __shared__ float sdt[8][16], su[8][16], sz[8][16], sB[8][16], sC[8][16];
    int tid = threadIdx.x;
    int s = tid & 15, dl = tid >> 4;
    int d0 = blockIdx.x * 16;
    int d = d0 + dl;
    float a_ds = -__expf(alog[d*16 + s]);
    float dsk  = dskip[d];
    float hst = 0.0f;
    for (int t0 = 0; t0 < SEQ; t0 += 8) {
        __syncthreads();
        if (tid < 128) {
            int tt = tid >> 4, j = tid & 15;
            int t = t0 + tt;
            sdt[tt][j] = dt[t*512 + d0 + j];
            su [tt][j] = u [t*512 + d0 + j];
            sz [tt][j] = xz[t*1024 + 512 + d0 + j];
        } else {
            int q = tid - 128;
            int tt = q >> 4, j = q & 15;
            int t = t0 + tt;
            sB[tt][j] = xdbl[t*48 + 16 + j];
            sC[tt][j] = xdbl[t*48 + 32 + j];
        }
        __syncthreads();
        #pragma unroll
        for (int tt = 0; tt < 8; ++tt) {
            float dtv = sdt[tt][dl];
            float uv  = su [tt][dl];
            hst = __expf(dtv * a_ds) * hst + dtv * uv * sB[tt][s];
            float p = hst * sC[tt][s];
            p += __shfl_xor(p, 1);
            p += __shfl_xor(p, 2);
            p += __shfl_xor(p, 4);
            p += __shfl_xor(p, 8);
            if (s == 0) {
                float zv = sz[tt][dl];
                float y = p + uv * dsk;
                yg[(t0+tt)*512 + d] = y * (zv / (1.0f + __expf(-zv)));
            }
        }
    }
}

// ---------------- final LN (f32 out) ----------------
__global__ __launch_bounds__(256) void lnf_kernel(
    const float* __restrict__ h, const float* __restrict__ w, const float* __restrict__ b,
    float* __restrict__ a_head)
{
    int tid = threadIdx.x;
    int lane = tid & 63;
    int r = tid >> 6;
    int row = blockIdx.x * 4 + r;
    float x0 = h[row*256 + lane];
    float x1 = h[row*256 + lane + 64];
    float x2 = h[row*256 + lane + 128];
    float x3 = h[row*256 + lane + 192];
    float s = x0 + x1 + x2 + x3;
    #pragma unroll
    for (int m = 1; m < 64; m <<= 1) s += __shfl_xor(s, m);
    float mean = s * (1.0f/256.0f);
    float d0 = x0-mean, d1 = x1-mean, d2 = x2-mean, d3 = x3-mean;
    float v = d0*d0 + d1*d1 + d2*d2 + d3*d3;
    #pragma unroll
    for (int m = 1; m < 64; m <<= 1) v += __shfl_xor(v, m);
    float rstd = rsqrtf(v * (1.0f/256.0f) + 1e-5f);
    a_head[row*256 + lane]     = d0*rstd*w[lane]     + b[lane];
    a_head[row*256 + lane+64]  = d1*rstd*w[lane+64]  + b[lane+64];
    a_head[row*256 + lane+128] = d2*rstd*w[lane+128] + b[lane+128];
    a_head[row*256 + lane+192] = d3*rstd*w[lane+192] + b[lane+192];
}

// ---------------- head GEMM (f32, LDS-tiled): out(128,32000) = AH(128,256) @ emb^T + hb ----------
// Block tile: 64 rows x 64 cols. A^T fully staged (256x68 pad), W staged in 32-k chunks.
// 16 outputs/thread via outer-product FMA. ~78 KB LDS -> 2 blocks/CU.
__global__ __launch_bounds__(256) void head_tiled_kernel(
    const float* __restrict__ AH, const float* __restrict__ emb,
    const float* __restrict__ hb, float* __restrict__ out)
{
    __shared__ float AT[256][68];
    __shared__ float WT[32][68];
    int tid = threadIdx.x;
    int r0 = blockIdx.y * 64;
    int c0 = blockIdx.x * 64;

    // stage A^T (coalesced global read; one-time)
    {
        int r  = tid >> 2;
        int kb = (tid & 3) * 64;
        #pragma unroll
        for (int i = 0; i < 16; ++i) {
            float4 a = *(const float4*)&AH[(size_t)(r0+r)*256 + kb + i*4];
            AT[kb+i*4+0][r] = a.x; AT[kb+i*4+1][r] = a.y;
            AT[kb+i*4+2][r] = a.z; AT[kb+i*4+3][r] = a.w;
        }
    }

    float acc[4][4] = {};
    int r4 = (tid >> 4) * 4;
    int c4 = (tid & 15) * 4;

    for (int kc = 0; kc < 256; kc += 32) {
        __syncthreads();
        // stage W chunk: 64 cols x 32 k (coalesced 32B/col-chunk reads)
        {
            int c  = tid >> 2;
            int kj = (tid & 3) * 8;
            const float* wp = &emb[(size_t)(c0+c)*256 + kc + kj];
            float4 w0 = *(const float4*)(wp);
            float4 w1 = *(const float4*)(wp + 4);
            WT[kj+0][c] = w0.x; WT[kj+1][c] = w0.y; WT[kj+2][c] = w0.z; WT[kj+3][c] = w0.w;
            WT[kj+4][c] = w1.x; WT[kj+5][c] = w1.y; WT[kj+6][c] = w1.z; WT[kj+7][c] = w1.w;
        }
        __syncthreads();
        #pragma unroll
        for (int k = 0; k < 32; ++k) {
            float4 av = *(const float4*)&AT[kc+k][r4];
            float4 wv = *(const float4*)&WT[k][c4];
            acc[0][0] += av.x*wv.x; acc[0][1] += av.x*wv.y; acc[0][2] += av.x*wv.z; acc[0][3] += av.x*wv.w;
            acc[1][0] += av.y*wv.x; acc[1][1] += av.y*wv.y; acc[1][2] += av.y*wv.z; acc[1][3] += av.y*wv.w;
            acc[2][0] += av.z*wv.x; acc[2][1] += av.z*wv.y; acc[2][2] += av.z*wv.z; acc[2][3] += av.z*wv.w;
            acc[3][0] += av.w*wv.x; acc[3][1] += av.w*wv.y; acc[3][2] += av.w*wv.z; acc[3][3] += av.w*wv.w;
        }
    }

    float4 hb4 = *(const float4*)&hb[c0 + c4];
    #pragma unroll
    for (int i = 0; i < 4; ++i) {
        float4 o;
        o.x = acc[i][0] + hb4.x;
        o.y = acc[i][1] + hb4.y;
        o.z = acc[i][2] + hb4.z;
        o.w = acc[i][3] + hb4.w;
        *(float4*)&out[(size_t)(r0+r4+i)*NVOCAB + c0 + c4] = o;
    }
}

// ---------------- launch ----------------
extern "C" void kernel_launch(void* const* d_in, const int* in_sizes, int n_in,
                              void* d_out, int out_size, void* d_ws, size_t ws_size,
                              hipStream_t stream)
{
    const int*   xin = (const int*)d_in[0];
    const float* emb = (const float*)d_in[1];
    const float* n1w = (const float*)d_in[2];
    const float* n1b = (const float*)d_in[3];
    const float* n2w = (const float*)d_in[4];
    const float* n2b = (const float*)d_in[5];
    const float* ipw = (const float*)d_in[6];
    const float* cw  = (const float*)d_in[7];
    const float* cb  = (const float*)d_in[8];
    const float* xpw = (const float*)d_in[9];
    const float* dpw = (const float*)d_in[10];
    const float* dpb = (const float*)d_in[11];
    const float* alog= (const float*)d_in[12];
    const float* dsk = (const float*)d_in[13];
    const float* opw = (const float*)d_in[14];
    const float* aiw = (const float*)d_in[15];
    const float* aib = (const float*)d_in[16];
    const float* aow = (const float*)d_in[17];
    const float* aob = (const float*)d_in[18];
    const float* nfw = (const float*)d_in[19];
    const float* nfb = (const float*)d_in[20];
    const float* hb  = (const float*)d_in[21];
    float* ws  = (float*)d_ws;
    float* out = (float*)d_out;

    embed_kernel<<<SEQ, 256, 0, stream>>>(xin, emb, ws + O_H);

    for (int l = 0; l < NLAYER; ++l) {
        // LN1 + in_proj -> xz (128 x 1024)
        gemv_kernel<256, 32, 2, GF_LN><<<dim3(128, 4), 256, 0, stream>>>(
            ws+O_H, n1w + l*256, n1b + l*256,
            ipw + (size_t)l*1024*256, nullptr, ws+O_XZ, 1024);
        // conv+silu + x_proj + dt_proj+softplus -> u, xdbl, dt
        convxdt_kernel<<<16, 256, 0, stream>>>(
            ws+O_XZ, cw + l*512*4, cb + l*512,
            xpw + (size_t)l*48*512, dpw + (size_t)l*512*16, dpb + l*512,
            ws+O_U, ws+O_XDBL, ws+O_DT);
        // selective scan + skip + gate -> yg
        scan_kernel<<<32, 256, 0, stream>>>(ws+O_DT, ws+O_U, ws+O_XDBL,
                                            alog + (size_t)l*512*16, dsk + l*512, ws+O_XZ, ws+O_YG);
        // out_proj, h += (N=256, K=512)
        gemv_kernel<512, 16, 2, GF_RESID><<<dim3(32, 8), 256, 0, stream>>>(
            ws+O_YG, nullptr, nullptr,
            opw + (size_t)l*256*512, nullptr, ws+O_H, 256);
        // LN2 + v-projection (+bias) -> v (attention over N identical tokens == v)
        gemv_kernel<256, 16, 2, GF_LN|GF_BIAS><<<dim3(32, 8), 256, 0, stream>>>(
            ws+O_H, n2w + l*256, n2b + l*256,
            aiw + (size_t)l*768*256 + (size_t)512*256, aib + l*768 + 512, ws+O_V, 256);
        // attn_out (+bias), h +=
        gemv_kernel<256, 16, 2, GF_BIAS|GF_RESID><<<dim3(32, 8), 256, 0, stream>>>(
            ws+O_V, nullptr, nullptr,
            aow + (size_t)l*256*256, aob + l*256, ws+O_H, 256);
    }

    // final LN, then tiled head GEMM + bias -> logits (f32)
    lnf_kernel<<<32, 256, 0, stream>>>(ws+O_H, nfw, nfb, ws+O_AH);
    head_tiled_kernel<<<dim3(NVOCAB/64, SEQ/64), 256, 0, stream>>>(ws+O_AH, emb, hb, out);
}